// Round 9
// baseline (605.501 us; speedup 1.0000x reference)
//
#include <hip/hip_runtime.h>
#include <hip/hip_fp16.h>
#include <math.h>

// LSTM: B=512, T=512, D=128, H=64. out = h_T [512,64] fp32.
// Phase 1 (xg_gemm2): xg = x@W_ih^T + b via bf16-MFMA (hi/lo x), CELL-MAJOR f16:
//   per (b,t,j) an 8B packet {i,f | g,o}.
// Phase 2 (lstm_rec7): 512 blocks x 256 thr. Block=batch row; wave tt=gate type;
//   lane j=cell. KEY FIX vs r4-r8: no full-memory fences in the t-loop. All four
//   prior designs converged at ~1265 cyc/step because __syncthreads / "memory"
//   clobber asm force s_waitcnt vmcnt(0) each step, draining the xg prefetch
//   (~600 cyc L3/HBM latency) onto the serial chain. Here: LDS-only waitcnt +
//   raw s_barrier + sched_barrier pinning; volatile LDS stores + laundered read
//   pointers defeat hoisting without touching vmcnt.

#define Bsz   512
#define Tlen  512
#define Din   128
#define Hdim  64
#define NGATE 256

typedef __attribute__((ext_vector_type(8))) short short8v;
typedef __attribute__((ext_vector_type(4))) float f32x4;
typedef __attribute__((ext_vector_type(2))) _Float16 h2v;
typedef unsigned short ushort_t;
typedef unsigned int uint_t;
typedef __attribute__((ext_vector_type(4))) uint_t uint4v;

__device__ __forceinline__ unsigned short f2bf_bits(float f) {
    union { float f; unsigned u; } v; v.f = f;
    unsigned r = v.u + 0x7fff + ((v.u >> 16) & 1);   // RNE
    return (unsigned short)(r >> 16);
}
__device__ __forceinline__ float bf2f(unsigned short b) {
    union { unsigned u; float f; } v; v.u = ((unsigned)b) << 16;
    return v.f;
}
__device__ __forceinline__ uint_t pkh(float a, float b) {   // pack 2xf16 (RNE)
    return (uint_t)__half_as_ushort(__float2half(a)) |
           ((uint_t)__half_as_ushort(__float2half(b)) << 16);
}
__device__ __forceinline__ h2v as_h2(uint_t u) {
    union { uint_t u; h2v h; } v; v.u = u; return v.h;
}
__device__ __forceinline__ float f16lo(uint_t u) {
    return __half2float(__ushort_as_half((ushort_t)(u & 0xffff)));
}
__device__ __forceinline__ float f16hi(uint_t u) {
    return __half2float(__ushort_as_half((ushort_t)(u >> 16)));
}
__device__ __forceinline__ float sigmoid_f(float v) {
    return 1.0f / (1.0f + __expf(-v));
}
__device__ __forceinline__ float tanh_f(float v) {
    float a = fabsf(v);
    float e = __expf(2.0f * a);
    float r = 1.0f - 2.0f / (e + 1.0f);
    return copysignf(r, v);
}

#if defined(__has_builtin)
#if __has_builtin(__builtin_amdgcn_fdot2)
#define FDOT2(a, b, c) __builtin_amdgcn_fdot2((a), (b), (c), false)
#endif
#endif
#ifndef FDOT2
#define FDOT2(a, b, c) fmaf((float)(a)[1], (float)(b)[1], fmaf((float)(a)[0], (float)(b)[0], (c)))
#endif

#define MF(acc, a, b) acc = __builtin_amdgcn_mfma_f32_16x16x32_bf16(a, b, acc, 0, 0, 0)

// LDS-only fence: waits DS ops, does NOT touch vmcnt (keeps xg prefetch in
// flight). sched_barrier pins placement (guide rule #18).
#define LDS_FENCE() do {                                   \
    __builtin_amdgcn_sched_barrier(0);                     \
    asm volatile("s_waitcnt lgkmcnt(0)");                  \
    __builtin_amdgcn_sched_barrier(0);                     \
} while (0)

// ---------------- Phase 1: xg cell-major f16 (unchanged, ~roofline) -----------
__global__ __launch_bounds__(256, 1)
void xg_gemm2(const float* __restrict__ x, const float* __restrict__ W_ih,
              const float* __restrict__ b_ih, const float* __restrict__ b_hh,
              uint_t* __restrict__ xg)
{
    __shared__ __align__(16) ushort_t sxh[2][16][136];  // x-tile hi (pad 136)
    __shared__ __align__(16) ushort_t sxl[2][16][136];  // x-tile lo

    const int tid = threadIdx.x;
    const int l = tid & 63, q = tid >> 6;
    const int jl = l & 15, s4 = l >> 4;
    const int rb = blockIdx.x & 31, tc = blockIdx.x >> 5;
    const int t0 = tc * 32;

    short8v wb[4][4];
    #pragma unroll
    for (int tt = 0; tt < 4; ++tt) {
        #pragma unroll
        for (int kt = 0; kt < 4; ++kt) {
            const float* wp = W_ih + (size_t)(tt * 64 + q * 16 + jl) * Din + kt * 32 + s4 * 8;
            f32x4 v0 = *(const f32x4*)wp;
            f32x4 v1 = *(const f32x4*)(wp + 4);
            #pragma unroll
            for (int j = 0; j < 8; ++j)
                wb[tt][kt][j] = (short)f2bf_bits((j < 4) ? v0[j] : v1[j - 4]);
        }
    }
    float bias[4];
    #pragma unroll
    for (int tt = 0; tt < 4; ++tt) {
        int g = tt * 64 + q * 16 + jl;
        bias[tt] = b_ih[g] + b_hh[g];
    }

    const int srow = tid >> 4, spart = tid & 15;
    const float* xrow = x + (size_t)(rb * 16 + srow) * Tlen * Din + spart * 8;
    f32x4 xr0 = *(const f32x4*)(xrow + (size_t)t0 * Din);
    f32x4 xr1 = *(const f32x4*)(xrow + (size_t)t0 * Din + 4);

    for (int ti = 0; ti < 32; ++ti) {
        const int t = t0 + ti, buf = ti & 1;

        short8v vh, vl;
        #pragma unroll
        for (int j = 0; j < 8; ++j) {
            float f = (j < 4) ? xr0[j] : xr1[j - 4];
            unsigned short hb = f2bf_bits(f);
            vh[j] = (short)hb;
            vl[j] = (short)f2bf_bits(f - bf2f(hb));
        }
        *(short8v*)&sxh[buf][srow][spart * 8] = vh;
        *(short8v*)&sxl[buf][srow][spart * 8] = vl;
        __syncthreads();

        if (ti + 1 < 32) {
            xr0 = *(const f32x4*)(xrow + (size_t)(t + 1) * Din);
            xr1 = *(const f32x4*)(xrow + (size_t)(t + 1) * Din + 4);
        }

        f32x4 acc0 = {0.f, 0.f, 0.f, 0.f}, acc1 = acc0, acc2 = acc0, acc3 = acc0;
        #pragma unroll
        for (int kt = 0; kt < 4; ++kt) {
            short8v ah = *(const short8v*)&sxh[buf][jl][kt * 32 + s4 * 8];
            short8v al = *(const short8v*)&sxl[buf][jl][kt * 32 + s4 * 8];
            MF(acc0, ah, wb[0][kt]); MF(acc1, ah, wb[1][kt]);
            MF(acc2, ah, wb[2][kt]); MF(acc3, ah, wb[3][kt]);
            MF(acc0, al, wb[0][kt]); MF(acc1, al, wb[1][kt]);
            MF(acc2, al, wb[2][kt]); MF(acc3, al, wb[3][kt]);
        }

        // C layout: col(gate-sub)=jl, row(batch-sub)=s4*4+r. Cell-major store.
        #pragma unroll
        for (int r = 0; r < 4; ++r) {
            const int brow = rb * 16 + s4 * 4 + r;
            uint2 st;
            st.x = pkh(acc0[r] + bias[0], acc1[r] + bias[1]);   // i, f
            st.y = pkh(acc2[r] + bias[2], acc3[r] + bias[3]);   // g, o
            *(uint2*)(xg + ((size_t)brow * Tlen + t) * 128 + (q * 16 + jl) * 2) = st;
        }
    }
}

// ---------------- Phase 2: gate-split recurrence, vmcnt-clean loop ------------
// 512 blocks x 256 thr (4 waves). Wave tt owns gate type tt; lane j owns cell j.
// Exchange PRE-activations (activations computed redundantly post-barrier).
__global__ __launch_bounds__(256, 1)
void lstm_rec7(const uint_t* __restrict__ xg, const float* __restrict__ W_hh,
               float* __restrict__ out)
{
    __shared__ float    gsh[2][4][Hdim];            // pre-activations, dbuf, 2KB
    __shared__ __align__(16) ushort_t hsh[4][Hdim]; // wave-private f16 h copies

    const int tid = threadIdx.x;
    const int j  = tid & 63;        // cell
    const int tt = tid >> 6;        // gate type: 0=i 1=f 2=g 3=o

    // W_hh row (tt*64 + j): 32 packed f16x2 in 8 uint4v (32 VGPRs).
    uint4v Wq[8];
    {
        const float2* wr = (const float2*)(W_hh + (size_t)(tt * Hdim + j) * Hdim);
        #pragma unroll
        for (int qq = 0; qq < 8; ++qq) {
            #pragma unroll
            for (int cc = 0; cc < 4; ++cc) {
                float2 w = wr[qq * 4 + cc];
                Wq[qq][cc] = pkh(w.x, w.y);
            }
        }
    }

    *(volatile ushort_t*)&hsh[tt][j] = 0;   // wave-private h0 = 0
    LDS_FENCE();
    float c = 0.0f, h = 0.0f;

    const int b = blockIdx.x;
    // cell-major xg: dword (tt>>1) of cell j's uint2 packet
    const uint_t* xp = xg + (size_t)b * (Tlen * 128) + j * 2 + (tt >> 1);
    uint_t xcur = xp[0];
    uint_t xnxt = xp[128];

    const ushort_t* hbase = &hsh[tt][0];
    const float* gbase0 = &gsh[0][0][0];
    const float* gbase1 = &gsh[1][0][0];

    for (int t = 0; t < Tlen; ++t) {
        // h(t): 8 laundered ds_read_b128 (wave-uniform broadcast; launder
        // defeats loop-invariant hoisting without any memory clobber)
        const uint4v* hp = (const uint4v*)hbase;
        asm("" : "+v"(hp));
        uint4v hq[8];
        #pragma unroll
        for (int i = 0; i < 8; ++i) hq[i] = hp[i];

        // prefetch xg(t+2) — stays in flight across the step (no vmcnt drain)
        const int tn = (t + 2 < Tlen) ? t + 2 : Tlen - 1;
        uint_t xpf = xp[(size_t)tn * 128];

        // pre-activation: xg gate + W_row . h   (32 fdot2, 4 chains of 8)
        float a0 = (tt & 1) ? f16hi(xcur) : f16lo(xcur);
        float a1 = 0.f, a2 = 0.f, a3 = 0.f;
        #pragma unroll
        for (int qq = 0; qq < 8; ++qq) {
            a0 = FDOT2(as_h2(hq[qq][0]), as_h2(Wq[qq][0]), a0);
            a1 = FDOT2(as_h2(hq[qq][1]), as_h2(Wq[qq][1]), a1);
            a2 = FDOT2(as_h2(hq[qq][2]), as_h2(Wq[qq][2]), a2);
            a3 = FDOT2(as_h2(hq[qq][3]), as_h2(Wq[qq][3]), a3);
        }
        float pre = (a0 + a1) + (a2 + a3);

        const int buf = t & 1;
        *(volatile float*)&gsh[buf][tt][j] = pre;

        // LDS-only drain + raw barrier (NO vmcnt drain — this is the fix)
        LDS_FENCE();
        __builtin_amdgcn_s_barrier();
        __builtin_amdgcn_sched_barrier(0);

        // all 4 pre-activations (laundered reads), activations redundant/wave
        const float* gp = buf ? gbase1 : gbase0;
        asm("" : "+v"(gp));
        float pi = gp[j];
        float pf = gp[Hdim + j];
        float pg = gp[2 * Hdim + j];
        float po = gp[3 * Hdim + j];

        float iv = sigmoid_f(pi);
        float fv = sigmoid_f(pf);
        float gv = tanh_f(pg);
        float ov = sigmoid_f(po);
        c = fv * c + iv * gv;
        h = ov * tanh_f(c);

        *(volatile ushort_t*)&hsh[tt][j] = __half_as_ushort(__float2half(h));
        LDS_FENCE();   // order h write vs next-iter laundered reads (same wave)

        xcur = xnxt;
        xnxt = xpf;
    }

    if (tt == 0) out[(size_t)b * Hdim + j] = h;
}

// ---------------- Fallback: round-1 fused kernel (proven correct) -------------
#define LDS_DWORDS 33920
__global__ void __launch_bounds__(256, 1)
lstm_fused(const float* __restrict__ x, const float* __restrict__ W_ih,
           const float* __restrict__ W_hh, const float* __restrict__ b_ih,
           const float* __restrict__ b_hh, float* __restrict__ out)
{
    extern __shared__ float lds[];
    float* wih   = lds;
    float* xbuf  = lds + 32768;
    float* gates = lds + 33280;
    float* hbuf  = lds + 33792;

    const int tid = threadIdx.x;
    const int g   = tid;
    const int row_base = blockIdx.x * 2;

    {
        const float4* src = reinterpret_cast<const float4*>(W_ih);
        float4* dst = reinterpret_cast<float4*>(wih);
        #pragma unroll
        for (int i = 0; i < 32; ++i) {
            int qq = i * 256 + tid;
            int rg = qq >> 5;
            int cc = qq & 31;
            dst[rg * 32 + (cc ^ (rg & 7))] = src[qq];
        }
    }
    float4 whh[16];
    {
        const float4* src = reinterpret_cast<const float4*>(W_hh) + g * 16;
        #pragma unroll
        for (int cc = 0; cc < 16; ++cc) whh[cc] = src[cc];
    }
    const float bias = b_ih[g] + b_hh[g];
    if (tid < 128) hbuf[tid] = 0.0f;
    {
        int r = tid >> 7, k = tid & 127;
        xbuf[tid] = x[((size_t)(row_base + r) * Tlen + 0) * Din + k];
    }
    float cstate = 0.0f, hval = 0.0f;
    __syncthreads();

    int cur = 0;
    const int sw = g & 7;
    const float4* w4 = reinterpret_cast<const float4*>(wih) + g * 32;

    for (int t = 0; t < Tlen; ++t) {
        float xnext = 0.0f;
        if (t + 1 < Tlen) {
            int r = tid >> 7, k = tid & 127;
            xnext = x[((size_t)(row_base + r) * Tlen + (t + 1)) * Din + k];
        }
        float acc0 = bias, acc1 = bias;
        {
            const float4* xr0 = reinterpret_cast<const float4*>(xbuf + cur * 256);
            const float4* xr1 = reinterpret_cast<const float4*>(xbuf + cur * 256 + 128);
            #pragma unroll 8
            for (int cc = 0; cc < 32; ++cc) {
                float4 w = w4[cc ^ sw];
                float4 a = xr0[cc];
                float4 bb = xr1[cc];
                acc0 += w.x * a.x + w.y * a.y + w.z * a.z + w.w * a.w;
                acc1 += w.x * bb.x + w.y * bb.y + w.z * bb.z + w.w * bb.w;
            }
        }
        {
            const float4* h0 = reinterpret_cast<const float4*>(hbuf);
            const float4* h1 = reinterpret_cast<const float4*>(hbuf + 64);
            #pragma unroll
            for (int cc = 0; cc < 16; ++cc) {
                float4 w = whh[cc];
                float4 a = h0[cc];
                float4 bb = h1[cc];
                acc0 += w.x * a.x + w.y * a.y + w.z * a.z + w.w * a.w;
                acc1 += w.x * bb.x + w.y * bb.y + w.z * bb.z + w.w * bb.w;
            }
        }
        gates[g]       = acc0;
        gates[256 + g] = acc1;
        __syncthreads();

        if (tid < 128) {
            int r = tid >> 6, jj = tid & 63;
            const float* gr = gates + r * 256;
            float ig = sigmoid_f(gr[jj]);
            float fg = sigmoid_f(gr[64 + jj]);
            float gg = tanh_f(gr[128 + jj]);
            float og = sigmoid_f(gr[192 + jj]);
            cstate = fg * cstate + ig * gg;
            hval   = og * tanh_f(cstate);
            hbuf[r * 64 + jj] = hval;
        }
        if (t + 1 < Tlen) xbuf[(cur ^ 1) * 256 + tid] = xnext;
        __syncthreads();
        cur ^= 1;
    }
    if (tid < 128) {
        int r = tid >> 6, jj = tid & 63;
        out[(size_t)(row_base + r) * Hdim + jj] = hval;
    }
}

extern "C" void kernel_launch(void* const* d_in, const int* in_sizes, int n_in,
                              void* d_out, int out_size, void* d_ws, size_t ws_size,
                              hipStream_t stream) {
    const float* x    = (const float*)d_in[0];
    const float* W_ih = (const float*)d_in[1];
    const float* W_hh = (const float*)d_in[2];
    const float* b_ih = (const float*)d_in[3];
    const float* b_hh = (const float*)d_in[4];
    float* out = (float*)d_out;

    const size_t need = (size_t)Bsz * Tlen * NGATE * 2;   // 134,217,728 B (f16 xg)
    if (ws_size >= need) {
        uint_t* xgws = (uint_t*)d_ws;
        xg_gemm2<<<512, 256, 0, stream>>>(x, W_ih, b_ih, b_hh, xgws);
        lstm_rec7<<<Bsz, 256, 0, stream>>>(xgws, W_hh, out);
    } else {
        const size_t lds_bytes = (size_t)LDS_DWORDS * 4;
        hipFuncSetAttribute(reinterpret_cast<const void*>(lstm_fused),
                            hipFuncAttributeMaxDynamicSharedMemorySize, (int)lds_bytes);
        lstm_fused<<<Bsz / 2, 256, lds_bytes, stream>>>(x, W_ih, W_hh, b_ih, b_hh, out);
    }
}

// Round 10
// 307.578 us; speedup vs baseline: 1.9686x; 1.9686x over previous
//
#include <hip/hip_runtime.h>
#include <hip/hip_fp16.h>
#include <math.h>

// LSTM: B=512, T=512, D=128, H=64. out = h_T [512,64] fp32.
// Phase 1 (xg_gemm2): xg = x@W_ih^T + b via bf16-MFMA (hi/lo x), CELL-MAJOR f16:
//   per (b,t,j) an 8B packet {i,f | g,o}.
// Phase 2 (lstm_rec8): r8's proven gate-split structure (4 waves, 1 barrier/step)
//   with BATCHED xg loads: 16 steps of xg pulled into registers per batch
//   (A/B double buffer). Rationale: __syncthreads drains vmcnt(0) every step;
//   with per-step prefetch that puts ~600cyc of L3/HBM latency on the serial
//   chain EVERY step (the r4-r8 ~1265cyc/step invariant). Batching makes the
//   drain hit outstanding loads only on the FIRST barrier of each 16-step batch
//   (~30 cyc/step amortized).

#define Bsz   512
#define Tlen  512
#define Din   128
#define Hdim  64
#define NGATE 256

typedef __attribute__((ext_vector_type(8))) short short8v;
typedef __attribute__((ext_vector_type(4))) float f32x4;
typedef __attribute__((ext_vector_type(2))) _Float16 h2v;
typedef unsigned short ushort_t;
typedef unsigned int uint_t;
typedef __attribute__((ext_vector_type(4))) uint_t uint4v;

__device__ __forceinline__ unsigned short f2bf_bits(float f) {
    union { float f; unsigned u; } v; v.f = f;
    unsigned r = v.u + 0x7fff + ((v.u >> 16) & 1);   // RNE
    return (unsigned short)(r >> 16);
}
__device__ __forceinline__ float bf2f(unsigned short b) {
    union { unsigned u; float f; } v; v.u = ((unsigned)b) << 16;
    return v.f;
}
__device__ __forceinline__ uint_t pkh(float a, float b) {   // pack 2xf16 (RNE)
    return (uint_t)__half_as_ushort(__float2half(a)) |
           ((uint_t)__half_as_ushort(__float2half(b)) << 16);
}
__device__ __forceinline__ h2v as_h2(uint_t u) {
    union { uint_t u; h2v h; } v; v.u = u; return v.h;
}
__device__ __forceinline__ float f16lo(uint_t u) {
    return __half2float(__ushort_as_half((ushort_t)(u & 0xffff)));
}
__device__ __forceinline__ float f16hi(uint_t u) {
    return __half2float(__ushort_as_half((ushort_t)(u >> 16)));
}
__device__ __forceinline__ float sigmoid_f(float v) {
    return 1.0f / (1.0f + __expf(-v));
}
__device__ __forceinline__ float tanh_f(float v) {
    float a = fabsf(v);
    float e = __expf(2.0f * a);
    float r = 1.0f - 2.0f / (e + 1.0f);
    return copysignf(r, v);
}

#if defined(__has_builtin)
#if __has_builtin(__builtin_amdgcn_fdot2)
#define FDOT2(a, b, c) __builtin_amdgcn_fdot2((a), (b), (c), false)
#endif
#endif
#ifndef FDOT2
#define FDOT2(a, b, c) fmaf((float)(a)[1], (float)(b)[1], fmaf((float)(a)[0], (float)(b)[0], (c)))
#endif

#define MF(acc, a, b) acc = __builtin_amdgcn_mfma_f32_16x16x32_bf16(a, b, acc, 0, 0, 0)

// ---------------- Phase 1: xg cell-major f16 (unchanged, ~roofline) -----------
__global__ __launch_bounds__(256, 1)
void xg_gemm2(const float* __restrict__ x, const float* __restrict__ W_ih,
              const float* __restrict__ b_ih, const float* __restrict__ b_hh,
              uint_t* __restrict__ xg)
{
    __shared__ __align__(16) ushort_t sxh[2][16][136];  // x-tile hi (pad 136)
    __shared__ __align__(16) ushort_t sxl[2][16][136];  // x-tile lo

    const int tid = threadIdx.x;
    const int l = tid & 63, q = tid >> 6;
    const int jl = l & 15, s4 = l >> 4;
    const int rb = blockIdx.x & 31, tc = blockIdx.x >> 5;
    const int t0 = tc * 32;

    short8v wb[4][4];
    #pragma unroll
    for (int tt = 0; tt < 4; ++tt) {
        #pragma unroll
        for (int kt = 0; kt < 4; ++kt) {
            const float* wp = W_ih + (size_t)(tt * 64 + q * 16 + jl) * Din + kt * 32 + s4 * 8;
            f32x4 v0 = *(const f32x4*)wp;
            f32x4 v1 = *(const f32x4*)(wp + 4);
            #pragma unroll
            for (int j = 0; j < 8; ++j)
                wb[tt][kt][j] = (short)f2bf_bits((j < 4) ? v0[j] : v1[j - 4]);
        }
    }
    float bias[4];
    #pragma unroll
    for (int tt = 0; tt < 4; ++tt) {
        int g = tt * 64 + q * 16 + jl;
        bias[tt] = b_ih[g] + b_hh[g];
    }

    const int srow = tid >> 4, spart = tid & 15;
    const float* xrow = x + (size_t)(rb * 16 + srow) * Tlen * Din + spart * 8;
    f32x4 xr0 = *(const f32x4*)(xrow + (size_t)t0 * Din);
    f32x4 xr1 = *(const f32x4*)(xrow + (size_t)t0 * Din + 4);

    for (int ti = 0; ti < 32; ++ti) {
        const int t = t0 + ti, buf = ti & 1;

        short8v vh, vl;
        #pragma unroll
        for (int j = 0; j < 8; ++j) {
            float f = (j < 4) ? xr0[j] : xr1[j - 4];
            unsigned short hb = f2bf_bits(f);
            vh[j] = (short)hb;
            vl[j] = (short)f2bf_bits(f - bf2f(hb));
        }
        *(short8v*)&sxh[buf][srow][spart * 8] = vh;
        *(short8v*)&sxl[buf][srow][spart * 8] = vl;
        __syncthreads();

        if (ti + 1 < 32) {
            xr0 = *(const f32x4*)(xrow + (size_t)(t + 1) * Din);
            xr1 = *(const f32x4*)(xrow + (size_t)(t + 1) * Din + 4);
        }

        f32x4 acc0 = {0.f, 0.f, 0.f, 0.f}, acc1 = acc0, acc2 = acc0, acc3 = acc0;
        #pragma unroll
        for (int kt = 0; kt < 4; ++kt) {
            short8v ah = *(const short8v*)&sxh[buf][jl][kt * 32 + s4 * 8];
            short8v al = *(const short8v*)&sxl[buf][jl][kt * 32 + s4 * 8];
            MF(acc0, ah, wb[0][kt]); MF(acc1, ah, wb[1][kt]);
            MF(acc2, ah, wb[2][kt]); MF(acc3, ah, wb[3][kt]);
            MF(acc0, al, wb[0][kt]); MF(acc1, al, wb[1][kt]);
            MF(acc2, al, wb[2][kt]); MF(acc3, al, wb[3][kt]);
        }

        // C layout: col(gate-sub)=jl, row(batch-sub)=s4*4+r. Cell-major store.
        #pragma unroll
        for (int r = 0; r < 4; ++r) {
            const int brow = rb * 16 + s4 * 4 + r;
            uint2 st;
            st.x = pkh(acc0[r] + bias[0], acc1[r] + bias[1]);   // i, f
            st.y = pkh(acc2[r] + bias[2], acc3[r] + bias[3]);   // g, o
            *(uint2*)(xg + ((size_t)brow * Tlen + t) * 128 + (q * 16 + jl) * 2) = st;
        }
    }
}

// ---------------- Phase 2: gate-split recurrence + batched xg loads -----------
// 512 blocks x 256 thr (4 waves). Wave tt owns gate type tt; lane j owns cell j.
// One barrier/step; xg pulled in 16-step register batches (A/B dbuf).
__global__ __launch_bounds__(256, 1)
void lstm_rec8(const uint_t* __restrict__ xg, const float* __restrict__ W_hh,
               float* __restrict__ out)
{
    __shared__ float    gsh[2][4][Hdim];            // activated gates, dbuf, 2KB
    __shared__ __align__(16) ushort_t hsh[4][Hdim]; // wave-private f16 h copies

    const int tid = threadIdx.x;
    const int j  = tid & 63;        // cell
    const int tt = tid >> 6;        // gate type: 0=i 1=f 2=g 3=o

    // W_hh row (tt*64 + j): 32 packed f16x2 in 8 uint4v (32 VGPRs).
    uint4v Wq[8];
    {
        const float2* wr = (const float2*)(W_hh + (size_t)(tt * Hdim + j) * Hdim);
        #pragma unroll
        for (int qq = 0; qq < 8; ++qq) {
            #pragma unroll
            for (int cc = 0; cc < 4; ++cc) {
                float2 w = wr[qq * 4 + cc];
                Wq[qq][cc] = pkh(w.x, w.y);
            }
        }
    }

    hsh[tt][j] = 0;                 // wave-private h0 = 0 (own wave reads only)
    asm volatile("" ::: "memory");
    float c = 0.0f, h = 0.0f;

    const int b = blockIdx.x;
    // cell-major xg: dword (tt>>1) of cell j's uint2 packet; stride/t = 128 dwords
    const uint_t* xp = xg + (size_t)b * (Tlen * 128) + j * 2 + (tt >> 1);

    // ---- batch prologue: batches 0 and 1 into registers -----------------------
    uint_t xA[16], xB[16];
    #pragma unroll
    for (int i = 0; i < 16; ++i) xA[i] = xp[(size_t)i * 128];
    #pragma unroll
    for (int i = 0; i < 16; ++i) xB[i] = xp[(size_t)(16 + i) * 128];

    const uint4v* hp = (const uint4v*)&hsh[tt][0];  // wave-private 128B

// One LSTM step consuming register xv (xg dword for this thread at step SI of
// the batch; SI parity == t parity since batches are 16-aligned).
#define STEP1(xv, SI) do {                                                     \
    uint4v hq[8];                                                              \
    _Pragma("unroll")                                                          \
    for (int i_ = 0; i_ < 8; ++i_) hq[i_] = hp[i_];                            \
    float a0 = (tt & 1) ? f16hi(xv) : f16lo(xv);                               \
    float a1 = 0.f, a2 = 0.f, a3 = 0.f;                                        \
    _Pragma("unroll")                                                          \
    for (int qq = 0; qq < 8; ++qq) {                                           \
        a0 = FDOT2(as_h2(hq[qq][0]), as_h2(Wq[qq][0]), a0);                    \
        a1 = FDOT2(as_h2(hq[qq][1]), as_h2(Wq[qq][1]), a1);                    \
        a2 = FDOT2(as_h2(hq[qq][2]), as_h2(Wq[qq][2]), a2);                    \
        a3 = FDOT2(as_h2(hq[qq][3]), as_h2(Wq[qq][3]), a3);                    \
    }                                                                          \
    float pre = (a0 + a1) + (a2 + a3);                                         \
    float act = (tt == 2) ? tanh_f(pre) : sigmoid_f(pre);                      \
    gsh[(SI) & 1][tt][j] = act;                                                \
    __syncthreads();                                                           \
    float iv = gsh[(SI) & 1][0][j];                                            \
    float fv = gsh[(SI) & 1][1][j];                                            \
    float gv = gsh[(SI) & 1][2][j];                                            \
    float ov = gsh[(SI) & 1][3][j];                                            \
    c = fv * c + iv * gv;                                                      \
    h = ov * tanh_f(c);                                                        \
    hsh[tt][j] = __half_as_ushort(__float2half(h));                            \
    asm volatile("" ::: "memory");                                             \
} while (0)

#define STEP16(XARR) do {                                                      \
    _Pragma("unroll")                                                          \
    for (int si_ = 0; si_ < 16; ++si_) STEP1(XARR[si_], si_);                  \
} while (0)

    for (int bt = 0; bt < 32; bt += 2) {
        STEP16(xA);
        if (bt + 2 < 32) {   // reload A with batch bt+2 (in flight ~1 batch)
            const uint_t* rp = xp + (size_t)(bt + 2) * 16 * 128;
            #pragma unroll
            for (int i = 0; i < 16; ++i) xA[i] = rp[(size_t)i * 128];
        }
        STEP16(xB);
        if (bt + 3 < 32) {   // reload B with batch bt+3
            const uint_t* rp = xp + (size_t)(bt + 3) * 16 * 128;
            #pragma unroll
            for (int i = 0; i < 16; ++i) xB[i] = rp[(size_t)i * 128];
        }
    }
#undef STEP16
#undef STEP1

    if (tt == 0) out[(size_t)b * Hdim + j] = h;
}

// ---------------- Fallback: round-1 fused kernel (proven correct) -------------
#define LDS_DWORDS 33920
__global__ void __launch_bounds__(256, 1)
lstm_fused(const float* __restrict__ x, const float* __restrict__ W_ih,
           const float* __restrict__ W_hh, const float* __restrict__ b_ih,
           const float* __restrict__ b_hh, float* __restrict__ out)
{
    extern __shared__ float lds[];
    float* wih   = lds;
    float* xbuf  = lds + 32768;
    float* gates = lds + 33280;
    float* hbuf  = lds + 33792;

    const int tid = threadIdx.x;
    const int g   = tid;
    const int row_base = blockIdx.x * 2;

    {
        const float4* src = reinterpret_cast<const float4*>(W_ih);
        float4* dst = reinterpret_cast<float4*>(wih);
        #pragma unroll
        for (int i = 0; i < 32; ++i) {
            int qq = i * 256 + tid;
            int rg = qq >> 5;
            int cc = qq & 31;
            dst[rg * 32 + (cc ^ (rg & 7))] = src[qq];
        }
    }
    float4 whh[16];
    {
        const float4* src = reinterpret_cast<const float4*>(W_hh) + g * 16;
        #pragma unroll
        for (int cc = 0; cc < 16; ++cc) whh[cc] = src[cc];
    }
    const float bias = b_ih[g] + b_hh[g];
    if (tid < 128) hbuf[tid] = 0.0f;
    {
        int r = tid >> 7, k = tid & 127;
        xbuf[tid] = x[((size_t)(row_base + r) * Tlen + 0) * Din + k];
    }
    float cstate = 0.0f, hval = 0.0f;
    __syncthreads();

    int cur = 0;
    const int sw = g & 7;
    const float4* w4 = reinterpret_cast<const float4*>(wih) + g * 32;

    for (int t = 0; t < Tlen; ++t) {
        float xnext = 0.0f;
        if (t + 1 < Tlen) {
            int r = tid >> 7, k = tid & 127;
            xnext = x[((size_t)(row_base + r) * Tlen + (t + 1)) * Din + k];
        }
        float acc0 = bias, acc1 = bias;
        {
            const float4* xr0 = reinterpret_cast<const float4*>(xbuf + cur * 256);
            const float4* xr1 = reinterpret_cast<const float4*>(xbuf + cur * 256 + 128);
            #pragma unroll 8
            for (int cc = 0; cc < 32; ++cc) {
                float4 w = w4[cc ^ sw];
                float4 a = xr0[cc];
                float4 bb = xr1[cc];
                acc0 += w.x * a.x + w.y * a.y + w.z * a.z + w.w * a.w;
                acc1 += w.x * bb.x + w.y * bb.y + w.z * bb.z + w.w * bb.w;
            }
        }
        {
            const float4* h0 = reinterpret_cast<const float4*>(hbuf);
            const float4* h1 = reinterpret_cast<const float4*>(hbuf + 64);
            #pragma unroll
            for (int cc = 0; cc < 16; ++cc) {
                float4 w = whh[cc];
                float4 a = h0[cc];
                float4 bb = h1[cc];
                acc0 += w.x * a.x + w.y * a.y + w.z * a.z + w.w * a.w;
                acc1 += w.x * bb.x + w.y * bb.y + w.z * bb.z + w.w * bb.w;
            }
        }
        gates[g]       = acc0;
        gates[256 + g] = acc1;
        __syncthreads();

        if (tid < 128) {
            int r = tid >> 6, jj = tid & 63;
            const float* gr = gates + r * 256;
            float ig = sigmoid_f(gr[jj]);
            float fg = sigmoid_f(gr[64 + jj]);
            float gg = tanh_f(gr[128 + jj]);
            float og = sigmoid_f(gr[192 + jj]);
            cstate = fg * cstate + ig * gg;
            hval   = og * tanh_f(cstate);
            hbuf[r * 64 + jj] = hval;
        }
        if (t + 1 < Tlen) xbuf[(cur ^ 1) * 256 + tid] = xnext;
        __syncthreads();
        cur ^= 1;
    }
    if (tid < 128) {
        int r = tid >> 6, jj = tid & 63;
        out[(size_t)(row_base + r) * Hdim + jj] = hval;
    }
}

extern "C" void kernel_launch(void* const* d_in, const int* in_sizes, int n_in,
                              void* d_out, int out_size, void* d_ws, size_t ws_size,
                              hipStream_t stream) {
    const float* x    = (const float*)d_in[0];
    const float* W_ih = (const float*)d_in[1];
    const float* W_hh = (const float*)d_in[2];
    const float* b_ih = (const float*)d_in[3];
    const float* b_hh = (const float*)d_in[4];
    float* out = (float*)d_out;

    const size_t need = (size_t)Bsz * Tlen * NGATE * 2;   // 134,217,728 B (f16 xg)
    if (ws_size >= need) {
        uint_t* xgws = (uint_t*)d_ws;
        xg_gemm2<<<512, 256, 0, stream>>>(x, W_ih, b_ih, b_hh, xgws);
        lstm_rec8<<<Bsz, 256, 0, stream>>>(xgws, W_hh, out);
    } else {
        const size_t lds_bytes = (size_t)LDS_DWORDS * 4;
        hipFuncSetAttribute(reinterpret_cast<const void*>(lstm_fused),
                            hipFuncAttributeMaxDynamicSharedMemorySize, (int)lds_bytes);
        lstm_fused<<<Bsz / 2, 256, lds_bytes, stream>>>(x, W_ih, W_hh, b_ih, b_hh, out);
    }
}